// Round 1
// baseline (632.267 us; speedup 1.0000x reference)
//
#include <hip/hip_runtime.h>

// ---------------------------------------------------------------------------
// Fused 2.5D window attention, one 256-thread block per window (B = 8192).
//   x:(8192,49,128) f32, w_qkv:(128,384) f32, w_out:(128,128) f32,
//   bias_table:(169,4) f32  ->  out:(8192,49,128) f32
// All GEMMs in bf16 MFMA (16x16x32), fp32 accumulation. Tokens padded 49->64.
// ---------------------------------------------------------------------------

typedef __bf16 bf16x8 __attribute__((ext_vector_type(8)));
typedef float f32x4 __attribute__((ext_vector_type(4)));
typedef unsigned short u16x8 __attribute__((ext_vector_type(8)));
typedef unsigned short u16x4 __attribute__((ext_vector_type(4)));

__device__ __forceinline__ unsigned short bf16rne(float f) {
  unsigned u = __builtin_bit_cast(unsigned, f);
  u += 0x7FFFu + ((u >> 16) & 1u);          // round-to-nearest-even
  return (unsigned short)(u >> 16);
}

__device__ __forceinline__ bf16x8 ld8(const unsigned short* p) {  // 16B aligned
  return __builtin_bit_cast(bf16x8, *(const u16x8*)p);
}

__device__ __forceinline__ bf16x8 ld8_b64(const unsigned short* p) {  // 8B aligned
  u16x4 lo = *(const u16x4*)p;
  u16x4 hi = *(const u16x4*)(p + 4);
  return __builtin_bit_cast(bf16x8,
         __builtin_shufflevector(lo, hi, 0, 1, 2, 3, 4, 5, 6, 7));
}

// ---------------------------------------------------------------------------
// Prelude: bf16-transpose both weights ([k][n] -> [n][k]) and expand the
// relative-position bias to bias_e[h][i 0..63][j 0..63] with -1e30 for j>=49.
// ---------------------------------------------------------------------------
__global__ void prep(const float* __restrict__ wq, const float* __restrict__ wo,
                     const float* __restrict__ bt,
                     unsigned short* __restrict__ wTq,
                     unsigned short* __restrict__ wTo,
                     float* __restrict__ bias_e) {
  int t = blockIdx.x * 256 + threadIdx.x;
  if (t < 49152) {                       // wTq[n*128+k] = bf16(wq[k*384+n])
    int n = t >> 7, k = t & 127;
    wTq[t] = bf16rne(wq[k * 384 + n]);
  } else if (t < 65536) {                // wTo[n*128+k] = bf16(wo[k*128+n])
    int i = t - 49152;
    int n = i >> 7, k = i & 127;
    wTo[i] = bf16rne(wo[k * 128 + n]);
  } else {                               // bias_e, 4*64*64 floats
    int i = t - 65536;                   // h*4096 + ii*64 + j
    int hh = i >> 12;
    int rem = i & 4095;
    int ii = rem >> 6, j = rem & 63;
    float v = -1e30f;                    // masks padded key columns j>=49
    if (j < 49) {
      int iq = ii < 49 ? ii : 48;        // padded query rows: any finite value
      int ri = iq / 7 - j / 7 + 6;
      int rj = iq % 7 - j % 7 + 6;
      v = bt[(ri * 13 + rj) * 4 + hh];
    }
    bias_e[i] = v;
  }
}

// ---------------------------------------------------------------------------
// Main fused kernel.
// LDS map (ushort units), total 26624 ushorts = 53248 B:
//   QS = 0      : qs[64][136]  (q * SCALE, bf16)        8704
//   KS = 8704   : ks[64][136]  (k, bf16)                8704
//   VS = 17408  : vsT[128][72] (v transposed: [dh][tok]) 9216
//   PS = 0      : ps[4][64][68] (softmax probs) -- overlays QS+KS after sync
//   OS = 0      : os[64][136]  (attn out)       -- overlays PS after sync
// All row strides are 16B multiples; fragment reads alias <=2 lanes/bank.
// ---------------------------------------------------------------------------
__global__ __launch_bounds__(256, 2) void attn_fused(
    const float* __restrict__ x,
    const unsigned short* __restrict__ wTq,
    const unsigned short* __restrict__ wTo,
    const float* __restrict__ bias_e,
    float* __restrict__ out) {
  __shared__ unsigned short lds[26624];
  constexpr int QS = 0, KS = 8704, VS = 17408, PS = 0, OS = 0;

  const int tid = threadIdx.x;
  const int wave = tid >> 6;
  const int lane = tid & 63;
  const int c16 = lane & 15;   // MFMA col / A-row lane index
  const int quad = lane >> 4;  // 0..3
  const int q4 = quad * 4;

  const float* xb = x + (size_t)blockIdx.x * 6272;
  const f32x4 zero4 = {0.f, 0.f, 0.f, 0.f};

  // ---------------- Phase 1: QKV = x @ w_qkv  (M=64, N=384, K=128) ---------
  // wave handles N-tiles [wave*6, wave*6+6)
  f32x4 acc[4][6];
#pragma unroll
  for (int m = 0; m < 4; ++m)
#pragma unroll
    for (int nt = 0; nt < 6; ++nt) acc[m][nt] = zero4;

  const u16x8* wq8 = (const u16x8*)wTq;
#pragma unroll
  for (int kk = 0; kk < 4; ++kk) {
    bf16x8 a[4];
#pragma unroll
    for (int m = 0; m < 4; ++m) {
      int row = m * 16 + c16;
      int rs = row < 49 ? row : 48;  // clamp: stay in-bounds
      const float4* p = (const float4*)(xb + rs * 128 + kk * 32 + quad * 8);
      float4 f0 = p[0], f1 = p[1];
      float fs[8] = {f0.x, f0.y, f0.z, f0.w, f1.x, f1.y, f1.z, f1.w};
      u16x8 u;
#pragma unroll
      for (int e = 0; e < 8; ++e)
        u[e] = (row < 49) ? bf16rne(fs[e]) : (unsigned short)0;
      a[m] = __builtin_bit_cast(bf16x8, u);
    }
    bf16x8 b[6];
#pragma unroll
    for (int nt = 0; nt < 6; ++nt) {
      int n = (wave * 6 + nt) * 16 + c16;
      b[nt] = __builtin_bit_cast(bf16x8, wq8[n * 16 + kk * 4 + quad]);
    }
#pragma unroll
    for (int nt = 0; nt < 6; ++nt)
#pragma unroll
      for (int m = 0; m < 4; ++m)
        acc[m][nt] =
            __builtin_amdgcn_mfma_f32_16x16x32_bf16(a[m], b[nt], acc[m][nt], 0, 0, 0);
  }

  // scatter D (row = m*16+q4+r, col = lane&15) into q / k / vT
#pragma unroll
  for (int nt = 0; nt < 6; ++nt) {
    int gn = (wave * 6 + nt) * 16 + c16;  // global qkv column, branch wave-uniform per nt
#pragma unroll
    for (int m = 0; m < 4; ++m)
#pragma unroll
      for (int r = 0; r < 4; ++r) {
        int row = m * 16 + q4 + r;
        float v = acc[m][nt][r];
        if (gn < 128)
          lds[QS + row * 136 + gn] = bf16rne(v * 0.17677669529663689f);  // q*SCALE
        else if (gn < 256)
          lds[KS + row * 136 + (gn - 128)] = bf16rne(v);
        else
          lds[VS + (gn - 256) * 72 + row] = bf16rne(v);  // v transposed [dh][token]
      }
  }
  __syncthreads();

  // ---------------- Phase 2: S = q @ k^T per head (wave = head) ------------
  const int h = wave;
  f32x4 s[4][4];
#pragma unroll
  for (int m = 0; m < 4; ++m)
#pragma unroll
    for (int nt = 0; nt < 4; ++nt) s[m][nt] = zero4;

  bf16x8 aq[4], bk[4];
#pragma unroll
  for (int m = 0; m < 4; ++m)
    aq[m] = ld8(&lds[QS + (m * 16 + c16) * 136 + h * 32 + quad * 8]);
#pragma unroll
  for (int nt = 0; nt < 4; ++nt)
    bk[nt] = ld8(&lds[KS + (nt * 16 + c16) * 136 + h * 32 + quad * 8]);
#pragma unroll
  for (int nt = 0; nt < 4; ++nt)
#pragma unroll
    for (int m = 0; m < 4; ++m)
      s[m][nt] = __builtin_amdgcn_mfma_f32_16x16x32_bf16(aq[m], bk[nt], s[m][nt], 0, 0, 0);

  // bias + exp (logits are tiny: no max-subtraction needed) + row sums
  const float* be = bias_e + h * 4096;
  float rinv[4][4];
#pragma unroll
  for (int m = 0; m < 4; ++m)
#pragma unroll
    for (int r = 0; r < 4; ++r) {
      int i = m * 16 + q4 + r;
      float rs = 0.f;
#pragma unroll
      for (int nt = 0; nt < 4; ++nt) {
        float e = __expf(s[m][nt][r] + be[i * 64 + nt * 16 + c16]);
        s[m][nt][r] = e;  // unnormalized prob
        rs += e;
      }
      rs += __shfl_xor(rs, 1);
      rs += __shfl_xor(rs, 2);
      rs += __shfl_xor(rs, 4);
      rs += __shfl_xor(rs, 8);
      rinv[m][r] = __builtin_amdgcn_rcpf(rs);  // folded into O-write later
    }
  __syncthreads();  // all qs/ks reads complete; ps may overlay them

  // write P (C-layout -> LDS -> A-layout, per guide m120)
#pragma unroll
  for (int m = 0; m < 4; ++m)
#pragma unroll
    for (int nt = 0; nt < 4; ++nt)
#pragma unroll
      for (int r = 0; r < 4; ++r)
        lds[PS + h * 4352 + (m * 16 + q4 + r) * 68 + nt * 16 + c16] =
            bf16rne(s[m][nt][r]);
  __syncthreads();

  // ---------------- Phase 3: O = P @ v  (M=64, N=32, K=64) -----------------
  f32x4 o[4][2];
#pragma unroll
  for (int m = 0; m < 4; ++m)
#pragma unroll
    for (int nt = 0; nt < 2; ++nt) o[m][nt] = zero4;

#pragma unroll
  for (int kk = 0; kk < 2; ++kk) {
    bf16x8 pa[4];
#pragma unroll
    for (int m = 0; m < 4; ++m)
      pa[m] = ld8_b64(&lds[PS + h * 4352 + (m * 16 + c16) * 68 + kk * 32 + quad * 8]);
#pragma unroll
    for (int nt = 0; nt < 2; ++nt) {
      bf16x8 bv = ld8(&lds[VS + (h * 32 + nt * 16 + c16) * 72 + kk * 32 + quad * 8]);
#pragma unroll
      for (int m = 0; m < 4; ++m)
        o[m][nt] = __builtin_amdgcn_mfma_f32_16x16x32_bf16(pa[m], bv, o[m][nt], 0, 0, 0);
    }
  }
  __syncthreads();  // all ps/vsT reads complete; os may overlay

  // write normalized O (rinv[m][r] lives in exactly the right lanes: S and O
  // share the C/D row mapping row=(lane>>4)*4+reg)
#pragma unroll
  for (int m = 0; m < 4; ++m)
#pragma unroll
    for (int nt = 0; nt < 2; ++nt)
#pragma unroll
      for (int r = 0; r < 4; ++r) {
        int row = m * 16 + q4 + r;
        lds[OS + row * 136 + h * 32 + nt * 16 + c16] =
            bf16rne(o[m][nt][r] * rinv[m][r]);
      }
  __syncthreads();

  // ---------------- Phase 4: out = O @ w_out  (M=64, N=128, K=128) ---------
  // wave handles N-tiles {2w, 2w+1}
  f32x4 oc[4][2];
#pragma unroll
  for (int m = 0; m < 4; ++m)
#pragma unroll
    for (int nt = 0; nt < 2; ++nt) oc[m][nt] = zero4;

  const u16x8* wo8 = (const u16x8*)wTo;
#pragma unroll
  for (int kk = 0; kk < 4; ++kk) {
    bf16x8 a2[4];
#pragma unroll
    for (int m = 0; m < 4; ++m)
      a2[m] = ld8(&lds[OS + (m * 16 + c16) * 136 + kk * 32 + quad * 8]);
#pragma unroll
    for (int nt = 0; nt < 2; ++nt) {
      int n = (wave * 2 + nt) * 16 + c16;
      bf16x8 b2 = __builtin_bit_cast(bf16x8, wo8[n * 16 + kk * 4 + quad]);
#pragma unroll
      for (int m = 0; m < 4; ++m)
        oc[m][nt] = __builtin_amdgcn_mfma_f32_16x16x32_bf16(a2[m], b2, oc[m][nt], 0, 0, 0);
    }
  }

  float* op = out + (size_t)blockIdx.x * 6272;
#pragma unroll
  for (int m = 0; m < 4; ++m)
#pragma unroll
    for (int r = 0; r < 4; ++r) {
      int row = m * 16 + q4 + r;
      if (row < 49) {
#pragma unroll
        for (int nt = 0; nt < 2; ++nt)
          op[row * 128 + (wave * 2 + nt) * 16 + c16] = oc[m][nt][r];
      }
    }
}

// ---------------------------------------------------------------------------
extern "C" void kernel_launch(void* const* d_in, const int* in_sizes, int n_in,
                              void* d_out, int out_size, void* d_ws, size_t ws_size,
                              hipStream_t stream) {
  const float* x = (const float*)d_in[0];
  const float* wq = (const float*)d_in[1];
  const float* wo = (const float*)d_in[2];
  const float* bt = (const float*)d_in[3];

  // workspace: wTq bf16 [384*128] | wTo bf16 [128*128] | bias_e f32 [4*64*64]
  unsigned short* wTq = (unsigned short*)d_ws;
  unsigned short* wTo = wTq + 49152;
  float* bias_e = (float*)((char*)d_ws + 131072);

  prep<<<320, 256, 0, stream>>>(wq, wo, bt, wTq, wTo, bias_e);
  attn_fused<<<8192, 256, 0, stream>>>(x, wTq, wTo, bias_e, (float*)d_out);
}

// Round 2
// 454.745 us; speedup vs baseline: 1.3904x; 1.3904x over previous
//
#include <hip/hip_runtime.h>

// ---------------------------------------------------------------------------
// Fused 2.5D window attention, one 256-thread block per window (B = 8192).
// Round 2: occupancy + VALU diet.
//   - LDS 37632 B (<=40960 -> 4 blocks/CU), regs capped 128 (launch_bounds 256,4)
//   - x staged to LDS as bf16 ONCE (swizzled), A-frags re-read from LDS
//   - offset M-tiles {0,16,32,33}: only token rows 0..48 exist anywhere
//   - per-head packed q/k/vT/P regions (wave-private), bias pre-vectorized
// ---------------------------------------------------------------------------

typedef __bf16 bf16x8 __attribute__((ext_vector_type(8)));
typedef float f32x4 __attribute__((ext_vector_type(4)));
typedef unsigned short u16x8 __attribute__((ext_vector_type(8)));
typedef unsigned short u16x4 __attribute__((ext_vector_type(4)));

__device__ __forceinline__ unsigned short bf16c(float f) {
  return __builtin_bit_cast(unsigned short, (__bf16)f);
}
__device__ __forceinline__ bf16x8 ld8(const unsigned short* p) {  // 16B aligned
  return __builtin_bit_cast(bf16x8, *(const u16x8*)p);
}

// LDS map (ushort units), total 18816 ush = 37632 B.
//  pre-B3:  XS [0,6272)  Q [6272,12544)  K [12544,18816)   (q/k per-head packed)
//  post-B3: VT [0,6656)  P [6656,16848)  OS [6656,13320)   (overlay XS/Q/K)
#define XSb 0
#define Qb  6272
#define Kb  12544
#define VTb 0
#define Pb  6656
#define OSb 6656

// ---------------------------------------------------------------------------
__global__ void prep(const float* __restrict__ wq, const float* __restrict__ wo,
                     const float* __restrict__ bt,
                     unsigned short* __restrict__ wTq,
                     unsigned short* __restrict__ wTo,
                     float* __restrict__ bias2) {
  int t = blockIdx.x * 256 + threadIdx.x;
  if (t < 49152) {                       // wTq[n*128+k] = bf16(wq[k*384+n]), SCALE folded into q cols
    int n = t >> 7, k = t & 127;
    float v = wq[k * 384 + n];
    if (n < 128) v *= 0.17677669529663689f;   // DIM_HEAD^-0.5
    wTq[t] = bf16c(v);
  } else if (t < 65536) {                // wTo[n*128+k] = bf16(wo[k*128+n])
    int i = t - 49152;
    int n = i >> 7, k = i & 127;
    wTo[i] = bf16c(wo[k * 128 + n]);
  } else {                               // bias2[((h*64+i)*16+c)*4+nt], j = nt*16+c
    int i = t - 65536;
    int nt = i & 3, c = (i >> 2) & 15, ii = (i >> 6) & 63, hh = i >> 12;
    int j = nt * 16 + c;
    float v = -1e30f;                    // masks key columns j>=49
    if (j < 49) {
      int iq = ii < 49 ? ii : 48;
      int ri = iq / 7 - j / 7 + 6;
      int rj = iq % 7 - j % 7 + 6;
      v = bt[(ri * 13 + rj) * 4 + hh];
    }
    bias2[i] = v;
  }
}

// ---------------------------------------------------------------------------
__global__ __launch_bounds__(256, 4) void attn_fused(
    const float* __restrict__ x,
    const unsigned short* __restrict__ wTq,
    const unsigned short* __restrict__ wTo,
    const float4* __restrict__ bias2,
    float* __restrict__ out) {
  __shared__ __align__(16) unsigned short lds[18816];

  const int tid = threadIdx.x;
  const int wave = tid >> 6;
  const int lane = tid & 63;
  const int c16 = lane & 15;
  const int quad = lane >> 4;
  const int q4 = quad * 4;
  const int h = wave;                 // wave == head
  const int MOFF[4] = {0, 16, 32, 33};  // offset M-tiles: rows 0..48 only

  const float* xb = x + (size_t)blockIdx.x * 6272;
  const f32x4 zero4 = {0.f, 0.f, 0.f, 0.f};

  // ---- stage x rows 0..48 -> XS bf16, granule(8-ush)-XOR-swizzled ---------
  for (int c = tid; c < 784; c += 256) {             // 49 rows x 16 chunks
    int row = c >> 4, c8 = c & 15;
    const float4* p = (const float4*)(xb + row * 128 + c8 * 8);
    float4 f0 = p[0], f1 = p[1];
    bf16x8 v;
    v[0] = (__bf16)f0.x; v[1] = (__bf16)f0.y; v[2] = (__bf16)f0.z; v[3] = (__bf16)f0.w;
    v[4] = (__bf16)f1.x; v[5] = (__bf16)f1.y; v[6] = (__bf16)f1.z; v[7] = (__bf16)f1.w;
    *(u16x8*)&lds[XSb + row * 128 + ((c8 ^ (row & 7)) << 3)] =
        __builtin_bit_cast(u16x8, v);
  }
  __syncthreads();  // B1: xs staged

  // ---- QKV = x @ w_qkv, per-head, 3 passes (q,k scattered; v held) --------
  const u16x8* wq8 = (const u16x8*)wTq;
  f32x4 vacc[4][2];
#pragma unroll
  for (int p = 0; p < 3; ++p) {
    f32x4 acc[4][2];
#pragma unroll
    for (int m = 0; m < 4; ++m) { acc[m][0] = zero4; acc[m][1] = zero4; }
#pragma unroll
    for (int kk = 0; kk < 4; ++kk) {
      bf16x8 a[4];
#pragma unroll
      for (int m = 0; m < 4; ++m) {
        int row = MOFF[m] + c16;
        a[m] = ld8(&lds[XSb + row * 128 + ((((kk << 2) | quad) ^ (row & 7)) << 3)]);
      }
      bf16x8 b[2];
#pragma unroll
      for (int j = 0; j < 2; ++j) {
        int n = (p * 8 + 2 * h + j) * 16 + c16;
        b[j] = __builtin_bit_cast(bf16x8, wq8[n * 16 + (kk << 2) + quad]);
      }
#pragma unroll
      for (int j = 0; j < 2; ++j)
#pragma unroll
        for (int m = 0; m < 4; ++m)
          acc[m][j] = __builtin_amdgcn_mfma_f32_16x16x32_bf16(a[m], b[j], acc[m][j], 0, 0, 0);
    }
    if (p < 2) {  // scatter q/k into per-head packed [49][32] (rows always <=48)
      int base = (p == 0 ? Qb : Kb) + h * 1568;
#pragma unroll
      for (int m = 0; m < 4; ++m)
#pragma unroll
        for (int j = 0; j < 2; ++j)
#pragma unroll
          for (int r = 0; r < 4; ++r)
            lds[base + (MOFF[m] + q4 + r) * 32 + j * 16 + c16] = bf16c(acc[m][j][r]);
    } else {
#pragma unroll
      for (int m = 0; m < 4; ++m) { vacc[m][0] = acc[m][0]; vacc[m][1] = acc[m][1]; }
    }
  }

  // ---- phase-2 fragment loads (before regions are overlaid) ---------------
  bf16x8 aq[4];
#pragma unroll
  for (int m = 0; m < 4; ++m)
    aq[m] = ld8(&lds[Qb + h * 1568 + (MOFF[m] + c16) * 32 + quad * 8]);
  bf16x8 bk[4];
#pragma unroll
  for (int nt = 0; nt < 3; ++nt)
    bk[nt] = ld8(&lds[Kb + h * 1568 + (nt * 16 + c16) * 32 + quad * 8]);
  {  // tile 3 = S-cols 48..63: col 48 real (lane c16==0), rest zero
    bf16x8 z;
#pragma unroll
    for (int e = 0; e < 8; ++e) z[e] = (__bf16)0.f;
    bk[3] = z;
    if (c16 == 0) bk[3] = ld8(&lds[Kb + h * 1568 + 48 * 32 + quad * 8]);
  }
  __syncthreads();  // B3: XS/Q/K dead -> VT/P zone may be written

  // ---- v: zero vT token-cols 49..51 (NaN guard), then scatter -------------
  {
    int dh = lane & 31;
    lds[VTb + h * 1664 + dh * 52 + 49 + (lane >> 5)] = 0;
    if (lane < 32) lds[VTb + h * 1664 + dh * 52 + 51] = 0;
  }
#pragma unroll
  for (int m = 0; m < 4; ++m)
#pragma unroll
    for (int j = 0; j < 2; ++j)
#pragma unroll
      for (int r = 0; r < 4; ++r)
        lds[VTb + h * 1664 + (j * 16 + c16) * 52 + MOFF[m] + q4 + r] = bf16c(vacc[m][j][r]);

  // ---- S = q@k^T per head, streamed per M-tile; P unnormalized ------------
  float rinv[4][4];
#pragma unroll
  for (int m = 0; m < 4; ++m) {
    f32x4 s[4];
#pragma unroll
    for (int nt = 0; nt < 4; ++nt)
      s[nt] = __builtin_amdgcn_mfma_f32_16x16x32_bf16(aq[m], bk[nt], zero4, 0, 0, 0);
    float4 b4[4];
#pragma unroll
    for (int r = 0; r < 4; ++r)
      b4[r] = bias2[h * 1024 + (MOFF[m] + q4 + r) * 16 + c16];
#pragma unroll
    for (int r = 0; r < 4; ++r) {
      int row = MOFF[m] + q4 + r;
      float e0 = __expf(s[0][r] + b4[r].x);
      float e1 = __expf(s[1][r] + b4[r].y);
      float e2 = __expf(s[2][r] + b4[r].z);
      float e3 = __expf(s[3][r] + b4[r].w);
      float rs = (e0 + e1) + (e2 + e3);
      rs += __shfl_xor(rs, 1);
      rs += __shfl_xor(rs, 2);
      rs += __shfl_xor(rs, 4);
      rs += __shfl_xor(rs, 8);
      rinv[m][r] = __builtin_amdgcn_rcpf(rs);
      unsigned short* pr = &lds[Pb + h * 2548 + row * 52 + c16];
      pr[0] = bf16c(e0);
      pr[16] = bf16c(e1);
      pr[32] = bf16c(e2);
      if (c16 < 4) pr[48] = bf16c(e3);   // cols 48..51 only (48 real, 49-51 = 0)
    }
  }

  // ---- O = P @ v (K = 64 tokens; tails masked in-register) ----------------
  bf16x8 pa[2][4];
#pragma unroll
  for (int kk = 0; kk < 2; ++kk)
#pragma unroll
    for (int m = 0; m < 4; ++m) {
      const unsigned short* pp = &lds[Pb + h * 2548 + (MOFF[m] + c16) * 52 + kk * 32 + quad * 8];
      u16x4 lo = *(const u16x4*)pp;
      u16x4 hi = *(const u16x4*)(pp + 4);
      if (kk == 1) {
        if (quad >= 2) hi = (u16x4)0;    // tokens 52..55 / 60..63
        if (quad == 3) lo = (u16x4)0;    // tokens 56..59
      }
      pa[kk][m] = __builtin_bit_cast(bf16x8,
                  __builtin_shufflevector(lo, hi, 0, 1, 2, 3, 4, 5, 6, 7));
    }
  bf16x8 bv[2][2];
#pragma unroll
  for (int kk = 0; kk < 2; ++kk)
#pragma unroll
    for (int j = 0; j < 2; ++j) {
      const unsigned short* vp = &lds[VTb + h * 1664 + (j * 16 + c16) * 52 + kk * 32 + quad * 8];
      u16x4 lo = *(const u16x4*)vp;
      u16x4 hi = *(const u16x4*)(vp + 4);
      if (kk == 1) {                     // symmetric mask: NaN-proof 0*0 products
        if (quad >= 2) hi = (u16x4)0;
        if (quad == 3) lo = (u16x4)0;
      }
      bv[kk][j] = __builtin_bit_cast(bf16x8,
                  __builtin_shufflevector(lo, hi, 0, 1, 2, 3, 4, 5, 6, 7));
    }
  __syncthreads();  // B4: all P/VT reads issued+drained; OS overlay allowed

  f32x4 o[4][2];
#pragma unroll
  for (int m = 0; m < 4; ++m) { o[m][0] = zero4; o[m][1] = zero4; }
#pragma unroll
  for (int kk = 0; kk < 2; ++kk)
#pragma unroll
    for (int j = 0; j < 2; ++j)
#pragma unroll
      for (int m = 0; m < 4; ++m)
        o[m][j] = __builtin_amdgcn_mfma_f32_16x16x32_bf16(pa[kk][m], bv[kk][j], o[m][j], 0, 0, 0);

  // normalized O -> OS (rinv lane-aligned: same offset row set as S)
#pragma unroll
  for (int m = 0; m < 4; ++m)
#pragma unroll
    for (int j = 0; j < 2; ++j)
#pragma unroll
      for (int r = 0; r < 4; ++r)
        lds[OSb + (MOFF[m] + q4 + r) * 136 + h * 32 + j * 16 + c16] =
            bf16c(o[m][j][r] * rinv[m][r]);
  __syncthreads();  // B5: OS ready (cross-wave read next)

  // ---- out = O @ w_out --------------------------------------------------
  const u16x8* wo8 = (const u16x8*)wTo;
  f32x4 oc[4][2];
#pragma unroll
  for (int m = 0; m < 4; ++m) { oc[m][0] = zero4; oc[m][1] = zero4; }
#pragma unroll
  for (int kk = 0; kk < 4; ++kk) {
    bf16x8 a2[4];
#pragma unroll
    for (int m = 0; m < 4; ++m)
      a2[m] = ld8(&lds[OSb + (MOFF[m] + c16) * 136 + kk * 32 + quad * 8]);
#pragma unroll
    for (int j = 0; j < 2; ++j) {
      int n = (2 * wave + j) * 16 + c16;
      bf16x8 b2 = __builtin_bit_cast(bf16x8, wo8[n * 16 + (kk << 2) + quad]);
#pragma unroll
      for (int m = 0; m < 4; ++m)
        oc[m][j] = __builtin_amdgcn_mfma_f32_16x16x32_bf16(a2[m], b2, oc[m][j], 0, 0, 0);
    }
  }

  float* op = out + (size_t)blockIdx.x * 6272;
#pragma unroll
  for (int m = 0; m < 4; ++m)
#pragma unroll
    for (int r = 0; r < 4; ++r) {
      int row = MOFF[m] + q4 + r;          // 0..48, all valid; 33-47 dup-identical
#pragma unroll
      for (int j = 0; j < 2; ++j)
        op[row * 128 + (2 * wave + j) * 16 + c16] = oc[m][j][r];
    }
}

// ---------------------------------------------------------------------------
extern "C" void kernel_launch(void* const* d_in, const int* in_sizes, int n_in,
                              void* d_out, int out_size, void* d_ws, size_t ws_size,
                              hipStream_t stream) {
  const float* x = (const float*)d_in[0];
  const float* wq = (const float*)d_in[1];
  const float* wo = (const float*)d_in[2];
  const float* bt = (const float*)d_in[3];

  // workspace: wTq bf16 [384*128] | wTo bf16 [128*128] | bias2 f32 [4*64*16*4]
  unsigned short* wTq = (unsigned short*)d_ws;
  unsigned short* wTo = wTq + 49152;
  float* bias2 = (float*)((char*)d_ws + 131072);

  prep<<<320, 256, 0, stream>>>(wq, wo, bt, wTq, wTo, bias2);
  attn_fused<<<8192, 256, 0, stream>>>(x, wTq, wTo, (const float4*)bias2, (float*)d_out);
}